// Round 7
// baseline (447.397 us; speedup 1.0000x reference)
//
#include <hip/hip_runtime.h>
#include <hip/hip_fp16.h>

#define F 64

typedef int v4i __attribute__((ext_vector_type(4)));

__device__ __forceinline__ float rlane(float v, int l) {
    return __uint_as_float(__builtin_amdgcn_readlane(__float_as_uint(v), l));
}

// ============ per-node in-degree ============
__global__ void k_count(const int* __restrict__ dst, int* count, int E) {
    int e = blockIdx.x * blockDim.x + threadIdx.x;
    if (e < E) atomicAdd(&count[__builtin_nontemporal_load(&dst[e])], 1);
}

// ============ scan of pad-4 counts -> row_start; also dis ============
__global__ void k_reduce(const int* __restrict__ c, int* __restrict__ bsum, int n) {
    __shared__ int s[256];
    int t = threadIdx.x;
    int i = blockIdx.x * 256 + t;
    s[t] = (i < n) ? ((c[i] + 3) & ~3) : 0;
    __syncthreads();
    for (int off = 128; off > 0; off >>= 1) {
        if (t < off) s[t] += s[t + off];
        __syncthreads();
    }
    if (t == 0) bsum[blockIdx.x] = s[0];
}

__global__ void k_scan_bsum(int* bs, int nb) {
    __shared__ int s[512];
    int t = threadIdx.x;
    int v = (t < nb) ? bs[t] : 0;
    s[t] = v;
    __syncthreads();
    for (int off = 1; off < 512; off <<= 1) {
        int x = (t >= off) ? s[t - off] : 0;
        __syncthreads();
        s[t] += x;
        __syncthreads();
    }
    if (t < nb) bs[t] = s[t] - v;  // exclusive
}

__global__ void k_scan_write(const int* __restrict__ c, const int* __restrict__ boff,
                             int* __restrict__ row_start, int* __restrict__ cursor,
                             float* __restrict__ dis, int n) {
    __shared__ int s[256];
    int t = threadIdx.x;
    int i = blockIdx.x * 256 + t;
    int cv = (i < n) ? c[i] : 0;
    int v = (cv + 3) & ~3;
    if (i >= n) v = 0;
    s[t] = v;
    __syncthreads();
    for (int off = 1; off < 256; off <<= 1) {
        int x = (t >= off) ? s[t - off] : 0;
        __syncthreads();
        s[t] += x;
        __syncthreads();
    }
    if (i <= n) {
        int excl = s[t] - v + boff[blockIdx.x];
        row_start[i] = excl;
        if (i < n) {
            cursor[i] = excl;
            dis[i] = rsqrtf((float)(cv + 1));
        }
    }
}

// write only the <=3 pad slots per row (zero-row index n); disjoint from data slots
__global__ void k_pad(const int* __restrict__ count, const int* __restrict__ row_start,
                      int* __restrict__ csr, int n) {
    int i = blockIdx.x * blockDim.x + threadIdx.x;
    if (i >= n) return;
    int e0 = row_start[i] + count[i];
    int e1 = row_start[i + 1];
    for (int p = e0; p < e1; ++p) csr[p] = n;
}

// ============ XCD-partitioned CSR fill, nt streaming reads ============
__global__ __launch_bounds__(256) void k_fillx(const int* __restrict__ src,
                                               const int* __restrict__ dst,
                                               int* cursor, int* __restrict__ csr,
                                               int E, int step) {
    int seg = blockIdx.x & 7;
    int e = (blockIdx.x >> 3) * 256 + threadIdx.x;
    if (e >= E) return;
    int d = __builtin_nontemporal_load(&dst[e]);
    unsigned rel = (unsigned)(d - seg * step);
    if (rel < (unsigned)step) {
        int sv = __builtin_nontemporal_load(&src[e]);
        int p = atomicAdd(&cursor[d], 1);
        csr[p] = sv;
    }
}

// ============ hs0 = fp16(dis * x), zero row at index n ============
__global__ void k_prep(const float* __restrict__ x, const float* __restrict__ dis,
                       __half* __restrict__ hs, int n) {
    int i = blockIdx.x * blockDim.x + threadIdx.x;
    int tot = (n + 1) * F;
    if (i >= tot) return;
    int row = i >> 6;
    hs[i] = __float2half((row < n) ? dis[row] * x[i] : 0.0f);
}

__global__ void k_zrow(__half* __restrict__ hs, int n) {
    hs[(size_t)n * F + threadIdx.x] = __float2half(0.0f);
}

// ============ fused GCN layer: 4 rows/wave, pad-4 CSR, fp16 storage ============
__global__ __launch_bounds__(256) void k_layer(const __half* __restrict__ hin,
                                               const float* __restrict__ W,
                                               const float* __restrict__ b,
                                               const int* __restrict__ row_start,
                                               const int* __restrict__ csr,
                                               const float* __restrict__ dis,
                                               __half* __restrict__ hout,
                                               int n, int scale_out) {
    __shared__ float Ws[F * F];
    int tid = threadIdx.x;
#pragma unroll
    for (int i = 0; i < 16; ++i) Ws[tid + i * 256] = W[tid + i * 256];
    __syncthreads();
    int lane = tid & 63;
    int r0 = (blockIdx.x * 4 + (tid >> 6)) * 4;
    if (r0 >= n) return;

    float acc0 = __half2float(hin[((size_t)(r0 + 0) << 6) + lane]);
    float acc1 = __half2float(hin[((size_t)(r0 + 1) << 6) + lane]);
    float acc2 = __half2float(hin[((size_t)(r0 + 2) << 6) + lane]);
    float acc3 = __half2float(hin[((size_t)(r0 + 3) << 6) + lane]);

    int s0 = row_start[r0];
    int s1 = row_start[r0 + 1];
    int s2 = row_start[r0 + 2];
    int s3 = row_start[r0 + 3];
    int s4 = row_start[r0 + 4];

    const v4i* p4 = (const v4i*)csr;
    int j = s0;
    // 2x-unrolled: 8 gathers in flight per iteration; batches are row-pure (pad-4)
    for (; j + 8 <= s4; j += 8) {
        v4i qa = __builtin_nontemporal_load(p4 + (j >> 2));
        v4i qb = __builtin_nontemporal_load(p4 + (j >> 2) + 1);
        float v0 = __half2float(hin[((size_t)qa.x << 6) + lane]);
        float v1 = __half2float(hin[((size_t)qa.y << 6) + lane]);
        float v2 = __half2float(hin[((size_t)qa.z << 6) + lane]);
        float v3 = __half2float(hin[((size_t)qa.w << 6) + lane]);
        float v4 = __half2float(hin[((size_t)qb.x << 6) + lane]);
        float v5 = __half2float(hin[((size_t)qb.y << 6) + lane]);
        float v6 = __half2float(hin[((size_t)qb.z << 6) + lane]);
        float v7 = __half2float(hin[((size_t)qb.w << 6) + lane]);
        float ta = (v0 + v1) + (v2 + v3);
        float tb = (v4 + v5) + (v6 + v7);
        if (j >= s3)      acc3 += ta;
        else if (j >= s2) acc2 += ta;
        else if (j >= s1) acc1 += ta;
        else              acc0 += ta;
        int j2 = j + 4;
        if (j2 >= s3)      acc3 += tb;
        else if (j2 >= s2) acc2 += tb;
        else if (j2 >= s1) acc1 += tb;
        else               acc0 += tb;
    }
    if (j < s4) {
        v4i qa = __builtin_nontemporal_load(p4 + (j >> 2));
        float v0 = __half2float(hin[((size_t)qa.x << 6) + lane]);
        float v1 = __half2float(hin[((size_t)qa.y << 6) + lane]);
        float v2 = __half2float(hin[((size_t)qa.z << 6) + lane]);
        float v3 = __half2float(hin[((size_t)qa.w << 6) + lane]);
        float ta = (v0 + v1) + (v2 + v3);
        if (j >= s3)      acc3 += ta;
        else if (j >= s2) acc2 += ta;
        else if (j >= s1) acc1 += ta;
        else              acc0 += ta;
    }

    acc0 *= dis[r0 + 0];
    acc1 *= dis[r0 + 1];
    acc2 *= dis[r0 + 2];
    acc3 *= dis[r0 + 3];

    float bb = b[lane];
    float y0 = bb, y1 = bb, y2 = bb, y3 = bb;
#pragma unroll
    for (int k = 0; k < F; ++k) {
        float w = Ws[(k << 6) + lane];
        y0 = fmaf(rlane(acc0, k), w, y0);
        y1 = fmaf(rlane(acc1, k), w, y1);
        y2 = fmaf(rlane(acc2, k), w, y2);
        y3 = fmaf(rlane(acc3, k), w, y3);
    }
    y0 = fmaxf(y0, 0.0f);
    y1 = fmaxf(y1, 0.0f);
    y2 = fmaxf(y2, 0.0f);
    y3 = fmaxf(y3, 0.0f);
    if (scale_out) {
        y0 *= dis[r0 + 0];
        y1 *= dis[r0 + 1];
        y2 *= dis[r0 + 2];
        y3 *= dis[r0 + 3];
    }
    hout[((size_t)(r0 + 0) << 6) + lane] = __float2half(y0);
    hout[((size_t)(r0 + 1) << 6) + lane] = __float2half(y1);
    hout[((size_t)(r0 + 2) << 6) + lane] = __float2half(y2);
    hout[((size_t)(r0 + 3) << 6) + lane] = __float2half(y3);
}

// ============ final 64->8 linear (fp16 input, fp32 math/out) ============
__global__ __launch_bounds__(256) void k_final(const __half* __restrict__ h,
                                               const float* __restrict__ Wl,
                                               const float* __restrict__ bl,
                                               float* __restrict__ out, int n) {
    __shared__ float Ws[F * 8];
    __shared__ float bs[8];
    int tid = threadIdx.x;
    Ws[tid] = Wl[tid];
    Ws[tid + 256] = Wl[tid + 256];
    if (tid < 8) bs[tid] = bl[tid];
    __syncthreads();
    int idx = blockIdx.x * 256 + tid;
    if (idx >= n * 8) return;
    int row = idx >> 3;
    int o = idx & 7;
    const __half* hr = h + (size_t)row * F;
    float acc = bs[o];
#pragma unroll
    for (int k = 0; k < F; ++k) acc = fmaf(__half2float(hr[k]), Ws[k * 8 + o], acc);
    out[idx] = acc;
}

extern "C" void kernel_launch(void* const* d_in, const int* in_sizes, int n_in,
                              void* d_out, int out_size, void* d_ws, size_t ws_size,
                              hipStream_t stream) {
    const float* x  = (const float*)d_in[0];
    const int*   ei = (const int*)d_in[1];
    const float* W1 = (const float*)d_in[2];
    const float* b1 = (const float*)d_in[3];
    const float* W2 = (const float*)d_in[4];
    const float* b2 = (const float*)d_in[5];
    const float* W3 = (const float*)d_in[6];
    const float* b3 = (const float*)d_in[7];
    const float* Wl = (const float*)d_in[8];
    const float* bl = (const float*)d_in[9];
    float* out = (float*)d_out;

    int n = in_sizes[0] / F;   // 100000 (n % 4 == 0)
    int E = in_sizes[1] / 2;   // 1600000
    const int* src = ei;
    const int* dst = ei + E;

    int np   = (n + 256) & ~255;          // >= n+1, multiple of 256
    int nb   = (np + 255) / 256;          // <=512 for k_scan_bsum
    int cap  = E + 3 * n + 64;            // worst-case pad-4 CSR size
    int step = (n + 7) / 8;               // 12500 nodes per XCD segment

    // workspace layout: ~38 MB total
    int*    count     = (int*)d_ws;
    int*    row_start = count + np;
    int*    cursor    = row_start + np;
    int*    bsum      = cursor + np;      // 512
    float*  dis       = (float*)(bsum + 512);
    int*    csr       = (int*)(dis + np);
    __half* buf1      = (__half*)(csr + ((cap + 3) & ~3));
    __half* buf2      = buf1 + (size_t)(n + 1) * F;

    int nb_e = (E + 255) / 256;

    // ---- degree ----
    hipMemsetAsync(count, 0, (size_t)np * sizeof(int), stream);
    k_count<<<nb_e, 256, 0, stream>>>(dst, count, E);

    // ---- row_start/cursor/dis ----
    k_reduce<<<nb, 256, 0, stream>>>(count, bsum, n);
    k_scan_bsum<<<1, 512, 0, stream>>>(bsum, nb);
    k_scan_write<<<nb, 256, 0, stream>>>(count, bsum, row_start, cursor, dis, n);

    // ---- CSR fill: pads + XCD-partitioned scatter ----
    k_pad<<<nb, 256, 0, stream>>>(count, row_start, csr, n);
    k_fillx<<<8 * nb_e, 256, 0, stream>>>(src, dst, cursor, csr, E, step);

    // ---- hs0 = fp16(dis*x), row n zeroed ----
    k_prep<<<((n + 1) * F + 255) / 256, 256, 0, stream>>>(x, dis, buf1, n);

    // ---- 3 fused layers, ping-pong ----
    int nb_l = (n / 4 + 3) / 4;
    k_layer<<<nb_l, 256, 0, stream>>>(buf1, W1, b1, row_start, csr, dis, buf2, n, 1);
    k_zrow<<<1, 64, 0, stream>>>(buf2, n);
    k_layer<<<nb_l, 256, 0, stream>>>(buf2, W2, b2, row_start, csr, dis, buf1, n, 1);
    k_layer<<<nb_l, 256, 0, stream>>>(buf1, W3, b3, row_start, csr, dis, buf2, n, 0);

    // ---- final linear ----
    k_final<<<(n * 8 + 255) / 256, 256, 0, stream>>>(buf2, Wl, bl, out, n);
}

// Round 8
// 412.780 us; speedup vs baseline: 1.0839x; 1.0839x over previous
//
#include <hip/hip_runtime.h>
#include <hip/hip_fp16.h>

#define F 64

typedef int v4i __attribute__((ext_vector_type(4)));

__device__ __forceinline__ float rlane(float v, int l) {
    return __uint_as_float(__builtin_amdgcn_readlane(__float_as_uint(v), l));
}

// ============ per-node in-degree ============
__global__ void k_count(const int* __restrict__ dst, int* count, int E) {
    int e = blockIdx.x * blockDim.x + threadIdx.x;
    if (e < E) atomicAdd(&count[__builtin_nontemporal_load(&dst[e])], 1);
}

// ============ scan of pad-4 counts -> row_start; also dis ============
__global__ void k_reduce(const int* __restrict__ c, int* __restrict__ bsum, int n) {
    __shared__ int s[256];
    int t = threadIdx.x;
    int i = blockIdx.x * 256 + t;
    s[t] = (i < n) ? ((c[i] + 3) & ~3) : 0;
    __syncthreads();
    for (int off = 128; off > 0; off >>= 1) {
        if (t < off) s[t] += s[t + off];
        __syncthreads();
    }
    if (t == 0) bsum[blockIdx.x] = s[0];
}

__global__ void k_scan_bsum(int* bs, int nb) {
    __shared__ int s[512];
    int t = threadIdx.x;
    int v = (t < nb) ? bs[t] : 0;
    s[t] = v;
    __syncthreads();
    for (int off = 1; off < 512; off <<= 1) {
        int x = (t >= off) ? s[t - off] : 0;
        __syncthreads();
        s[t] += x;
        __syncthreads();
    }
    if (t < nb) bs[t] = s[t] - v;  // exclusive
}

__global__ void k_scan_write(const int* __restrict__ c, const int* __restrict__ boff,
                             int* __restrict__ row_start, int* __restrict__ cursor,
                             float* __restrict__ dis, int n) {
    __shared__ int s[256];
    int t = threadIdx.x;
    int i = blockIdx.x * 256 + t;
    int cv = (i < n) ? c[i] : 0;
    int v = (cv + 3) & ~3;
    if (i >= n) v = 0;
    s[t] = v;
    __syncthreads();
    for (int off = 1; off < 256; off <<= 1) {
        int x = (t >= off) ? s[t - off] : 0;
        __syncthreads();
        s[t] += x;
        __syncthreads();
    }
    if (i <= n) {
        int excl = s[t] - v + boff[blockIdx.x];
        row_start[i] = excl;
        if (i < n) {
            cursor[i] = excl;
            dis[i] = rsqrtf((float)(cv + 1));
        }
    }
}

// write only the <=3 pad slots per row (zero-row index n)
__global__ void k_pad(const int* __restrict__ count, const int* __restrict__ row_start,
                      int* __restrict__ csr, int n) {
    int i = blockIdx.x * blockDim.x + threadIdx.x;
    if (i >= n) return;
    int e0 = row_start[i] + count[i];
    int e1 = row_start[i + 1];
    for (int p = e0; p < e1; ++p) csr[p] = n;
}

// ============ XCD-partitioned CSR fill, nt streaming reads ============
__global__ __launch_bounds__(256) void k_fillx(const int* __restrict__ src,
                                               const int* __restrict__ dst,
                                               int* cursor, int* __restrict__ csr,
                                               int E, int step) {
    int seg = blockIdx.x & 7;
    int e = (blockIdx.x >> 3) * 256 + threadIdx.x;
    if (e >= E) return;
    int d = __builtin_nontemporal_load(&dst[e]);
    unsigned rel = (unsigned)(d - seg * step);
    if (rel < (unsigned)step) {
        int sv = __builtin_nontemporal_load(&src[e]);
        int p = atomicAdd(&cursor[d], 1);
        csr[p] = sv;
    }
}

// ============ hs0 = fp16(dis * x), zero row at index n ============
__global__ void k_prep(const float* __restrict__ x, const float* __restrict__ dis,
                       __half* __restrict__ hs, int n) {
    int i = blockIdx.x * blockDim.x + threadIdx.x;
    int tot = (n + 1) * F;
    if (i >= tot) return;
    int row = i >> 6;
    hs[i] = __float2half((row < n) ? dis[row] * x[i] : 0.0f);
}

__global__ void k_zrow(__half* __restrict__ hs, int n) {
    hs[(size_t)n * F + threadIdx.x] = __float2half(0.0f);
}

__device__ __forceinline__ void h4acc(uint2 u, float* t) {
    float2 fa = __half22float2(*(__half2*)&u.x);
    float2 fb = __half22float2(*(__half2*)&u.y);
    t[0] += fa.x; t[1] += fa.y; t[2] += fb.x; t[3] += fb.y;
}

// ============ fused GCN layer: wide-gather version ============
// 4 dst rows per wave. Lane = (group g = lane>>4) x (feature quad sub = lane&15).
// One iteration covers 16 csr slots: 1 int4 index load + 4 uint2 (8B) gathers
// per lane; each gather instruction fetches 4 src rows (512 B payload).
// Batches of 4 slots are row-pure (pad-4), attribution is per-lane predicated.
__global__ __launch_bounds__(256) void k_layer(const __half* __restrict__ hin,
                                               const float* __restrict__ W,
                                               const float* __restrict__ b,
                                               const int* __restrict__ row_start,
                                               const int* __restrict__ csr,
                                               const float* __restrict__ dis,
                                               __half* __restrict__ hout,
                                               int n, int scale_out) {
    __shared__ float Ws[F * F];
    int tid = threadIdx.x;
#pragma unroll
    for (int i = 0; i < 16; ++i) Ws[tid + i * 256] = W[tid + i * 256];
    __syncthreads();
    int lane = tid & 63;
    int g = lane >> 4;       // 0..3
    int sub = lane & 15;     // features [4*sub, 4*sub+4)
    int r0 = (blockIdx.x * 4 + (tid >> 6)) * 4;
    if (r0 >= n) return;

    int s0 = row_start[r0];
    int s1 = row_start[r0 + 1];
    int s2 = row_start[r0 + 2];
    int s3 = row_start[r0 + 3];
    int s4 = row_start[r0 + 4];

    float a0[4] = {0, 0, 0, 0};
    float a1[4] = {0, 0, 0, 0};
    float a2[4] = {0, 0, 0, 0};
    float a3[4] = {0, 0, 0, 0};

    const v4i* csr4 = (const v4i*)csr;
    const uint2* h2 = (const uint2*)hin;
    int B0 = s0 >> 2, B4 = s4 >> 2;
    for (int bb = B0; bb < B4; bb += 4) {
        int mybb = bb + g;
        bool valid = mybb < B4;
        v4i q = __builtin_nontemporal_load(csr4 + (valid ? mybb : B0));
        if (!valid) { q.x = n; q.y = n; q.z = n; q.w = n; }
        int slot = mybb << 2;
        int r = (slot >= s1) + ((slot >= s2) + (slot >= s3));
        uint2 qa = h2[((size_t)q.x << 4) + sub];
        uint2 qb = h2[((size_t)q.y << 4) + sub];
        uint2 qc = h2[((size_t)q.z << 4) + sub];
        uint2 qd = h2[((size_t)q.w << 4) + sub];
        float t[4] = {0, 0, 0, 0};
        h4acc(qa, t); h4acc(qb, t); h4acc(qc, t); h4acc(qd, t);
        float m0 = (r == 0) ? 1.0f : 0.0f;
        float m1 = (r == 1) ? 1.0f : 0.0f;
        float m2 = (r == 2) ? 1.0f : 0.0f;
        float m3 = (r == 3) ? 1.0f : 0.0f;
#pragma unroll
        for (int m = 0; m < 4; ++m) {
            a0[m] = fmaf(m0, t[m], a0[m]);
            a1[m] = fmaf(m1, t[m], a1[m]);
            a2[m] = fmaf(m2, t[m], a2[m]);
            a3[m] = fmaf(m3, t[m], a3[m]);
        }
    }

    // reduce partials across the 4 lane-groups (xor 16, 32)
#pragma unroll
    for (int m = 0; m < 4; ++m) {
        a0[m] += __shfl_xor(a0[m], 16); a0[m] += __shfl_xor(a0[m], 32);
        a1[m] += __shfl_xor(a1[m], 16); a1[m] += __shfl_xor(a1[m], 32);
        a2[m] += __shfl_xor(a2[m], 16); a2[m] += __shfl_xor(a2[m], 32);
        a3[m] += __shfl_xor(a3[m], 16); a3[m] += __shfl_xor(a3[m], 32);
    }

    // self-loop terms (hs already carries dis factor), then dis[dst] scale
    {
        uint2 u0 = h2[((size_t)(r0 + 0) << 4) + sub];
        uint2 u1 = h2[((size_t)(r0 + 1) << 4) + sub];
        uint2 u2 = h2[((size_t)(r0 + 2) << 4) + sub];
        uint2 u3 = h2[((size_t)(r0 + 3) << 4) + sub];
        h4acc(u0, a0); h4acc(u1, a1); h4acc(u2, a2); h4acc(u3, a3);
    }
    float d0 = dis[r0 + 0], d1 = dis[r0 + 1], d2 = dis[r0 + 2], d3 = dis[r0 + 3];
#pragma unroll
    for (int m = 0; m < 4; ++m) {
        a0[m] *= d0; a1[m] *= d1; a2[m] *= d2; a3[m] *= d3;
    }

    // transform: y_r[lane] = sum_k acc_r[k] * W[k][lane] + b[lane]
    // acc_r[k], k = 4*a + m, lives in lane a (groups replicated after reduce)
    float bb_ = b[lane];
    float y0 = bb_, y1 = bb_, y2 = bb_, y3 = bb_;
#pragma unroll
    for (int a = 0; a < 16; ++a) {
#pragma unroll
        for (int m = 0; m < 4; ++m) {
            float w = Ws[(((a << 2) + m) << 6) + lane];
            y0 = fmaf(rlane(a0[m], a), w, y0);
            y1 = fmaf(rlane(a1[m], a), w, y1);
            y2 = fmaf(rlane(a2[m], a), w, y2);
            y3 = fmaf(rlane(a3[m], a), w, y3);
        }
    }
    y0 = fmaxf(y0, 0.0f);
    y1 = fmaxf(y1, 0.0f);
    y2 = fmaxf(y2, 0.0f);
    y3 = fmaxf(y3, 0.0f);
    if (scale_out) { y0 *= d0; y1 *= d1; y2 *= d2; y3 *= d3; }
    hout[((size_t)(r0 + 0) << 6) + lane] = __float2half(y0);
    hout[((size_t)(r0 + 1) << 6) + lane] = __float2half(y1);
    hout[((size_t)(r0 + 2) << 6) + lane] = __float2half(y2);
    hout[((size_t)(r0 + 3) << 6) + lane] = __float2half(y3);
}

// ============ final 64->8 linear (fp16 input, fp32 math/out) ============
__global__ __launch_bounds__(256) void k_final(const __half* __restrict__ h,
                                               const float* __restrict__ Wl,
                                               const float* __restrict__ bl,
                                               float* __restrict__ out, int n) {
    __shared__ float Ws[F * 8];
    __shared__ float bs[8];
    int tid = threadIdx.x;
    Ws[tid] = Wl[tid];
    Ws[tid + 256] = Wl[tid + 256];
    if (tid < 8) bs[tid] = bl[tid];
    __syncthreads();
    int idx = blockIdx.x * 256 + tid;
    if (idx >= n * 8) return;
    int row = idx >> 3;
    int o = idx & 7;
    const __half* hr = h + (size_t)row * F;
    float acc = bs[o];
#pragma unroll
    for (int k = 0; k < F; ++k) acc = fmaf(__half2float(hr[k]), Ws[k * 8 + o], acc);
    out[idx] = acc;
}

extern "C" void kernel_launch(void* const* d_in, const int* in_sizes, int n_in,
                              void* d_out, int out_size, void* d_ws, size_t ws_size,
                              hipStream_t stream) {
    const float* x  = (const float*)d_in[0];
    const int*   ei = (const int*)d_in[1];
    const float* W1 = (const float*)d_in[2];
    const float* b1 = (const float*)d_in[3];
    const float* W2 = (const float*)d_in[4];
    const float* b2 = (const float*)d_in[5];
    const float* W3 = (const float*)d_in[6];
    const float* b3 = (const float*)d_in[7];
    const float* Wl = (const float*)d_in[8];
    const float* bl = (const float*)d_in[9];
    float* out = (float*)d_out;

    int n = in_sizes[0] / F;   // 100000 (n % 4 == 0)
    int E = in_sizes[1] / 2;   // 1600000
    const int* src = ei;
    const int* dst = ei + E;

    int np   = (n + 256) & ~255;          // >= n+1, multiple of 256
    int nb   = (np + 255) / 256;          // <=512 for k_scan_bsum
    int cap  = E + 3 * n + 64;            // worst-case pad-4 CSR size (+tail slack)
    int step = (n + 7) / 8;               // 12500 nodes per XCD segment

    // workspace layout: ~38 MB total (all segments 16B aligned)
    int*    count     = (int*)d_ws;
    int*    row_start = count + np;
    int*    cursor    = row_start + np;
    int*    bsum      = cursor + np;      // 512
    float*  dis       = (float*)(bsum + 512);
    int*    csr       = (int*)(dis + np);
    __half* buf1      = (__half*)(csr + ((cap + 3) & ~3));
    __half* buf2      = buf1 + (size_t)(n + 1) * F;

    int nb_e = (E + 255) / 256;

    // ---- degree ----
    hipMemsetAsync(count, 0, (size_t)np * sizeof(int), stream);
    k_count<<<nb_e, 256, 0, stream>>>(dst, count, E);

    // ---- row_start/cursor/dis ----
    k_reduce<<<nb, 256, 0, stream>>>(count, bsum, n);
    k_scan_bsum<<<1, 512, 0, stream>>>(bsum, nb);
    k_scan_write<<<nb, 256, 0, stream>>>(count, bsum, row_start, cursor, dis, n);

    // ---- CSR fill: pads + XCD-partitioned scatter ----
    k_pad<<<nb, 256, 0, stream>>>(count, row_start, csr, n);
    k_fillx<<<8 * nb_e, 256, 0, stream>>>(src, dst, cursor, csr, E, step);

    // ---- hs0 = fp16(dis*x), row n zeroed ----
    k_prep<<<((n + 1) * F + 255) / 256, 256, 0, stream>>>(x, dis, buf1, n);

    // ---- 3 fused layers, ping-pong ----
    int nb_l = (n / 4 + 3) / 4;
    k_layer<<<nb_l, 256, 0, stream>>>(buf1, W1, b1, row_start, csr, dis, buf2, n, 1);
    k_zrow<<<1, 64, 0, stream>>>(buf2, n);
    k_layer<<<nb_l, 256, 0, stream>>>(buf2, W2, b2, row_start, csr, dis, buf1, n, 1);
    k_layer<<<nb_l, 256, 0, stream>>>(buf1, W3, b3, row_start, csr, dis, buf2, n, 0);

    // ---- final linear ----
    k_final<<<(n * 8 + 255) / 256, 256, 0, stream>>>(buf2, Wl, bl, out, n);
}